// Round 1
// baseline (51.260 us; speedup 1.0000x reference)
//
#include <hip/hip_runtime.h>
#include <hip/hip_bf16.h>

#define N_W 96
#define N_F 96
#define NP1 97                 // N_F+1 == N_W+1
#define W_ELEMS (N_W * NP1 * NP1)   // 903264
#define R_ELEMS ((N_W + N_F) * (N_W + N_F))  // 36864
#define TOTAL_DECODE (2 * W_ELEMS + R_ELEMS)

// Decode one-hot tensors into index form.
// pw[i*97+k] = firm at rank k for worker i; pf[f*97+k] = worker at rank k for firm f;
// ord[r] = dictating agent (0..95 worker, 96..191 firm) in round r.
__global__ __launch_bounds__(256) void decode_kernel(
    const float* __restrict__ W, const float* __restrict__ F,
    const float* __restrict__ R,
    short* __restrict__ pw, short* __restrict__ pf, short* __restrict__ ord) {
    int idx = blockIdx.x * blockDim.x + threadIdx.x;
    if (idx < W_ELEMS) {
        if (W[idx] > 0.5f) {
            int i = idx / (NP1 * NP1);
            int rem = idx - i * NP1 * NP1;
            int j = rem / NP1;
            int k = rem - j * NP1;
            pw[i * NP1 + k] = (short)j;
        }
    } else if (idx < 2 * W_ELEMS) {
        int e = idx - W_ELEMS;
        if (F[e] > 0.5f) {
            int i = e / (NP1 * NP1);
            int rem = e - i * NP1 * NP1;
            int j = rem / NP1;
            int k = rem - j * NP1;
            pf[i * NP1 + k] = (short)j;
        }
    } else if (idx < TOTAL_DECODE) {
        int e = idx - 2 * W_ELEMS;
        if (R[e] > 0.5f) {
            int a = e / (N_W + N_F);
            int r = e - a * (N_W + N_F);
            ord[r] = (short)a;
        }
    }
}

// Single-block sequential serial dictatorship.
__global__ __launch_bounds__(256) void sd_kernel(
    const short* __restrict__ pw_g, const short* __restrict__ pf_g,
    const short* __restrict__ ord_g, float* __restrict__ out) {
    __shared__ short s_pw[N_W * NP1];
    __shared__ short s_pf[N_F * NP1];
    __shared__ short s_ord[N_W + N_F];
    __shared__ unsigned char s_m[NP1 * NP1];     // match matrix (0/1)
    __shared__ unsigned char rem_firm[NP1];      // firm row removed from worker matrices
    __shared__ unsigned char rem_work[NP1];      // worker row removed from firm matrices
    __shared__ unsigned char zero_f[N_F];        // firm matrix annihilated (was chosen)
    __shared__ unsigned char zero_w[N_W];        // worker matrix annihilated (was chosen)

    const int t = threadIdx.x;
    for (int i = t; i < N_W * NP1; i += 256) { s_pw[i] = pw_g[i]; s_pf[i] = pf_g[i]; }
    for (int i = t; i < N_W + N_F; i += 256) s_ord[i] = ord_g[i];
    for (int i = t; i < NP1 * NP1; i += 256) s_m[i] = 0;
    if (t < NP1) { rem_firm[t] = 0; rem_work[t] = 0; }
    if (t < N_W) { zero_w[t] = 0; zero_f[t] = 0; }
    __syncthreads();

    if (t < 64) {  // one wave runs the sequential rounds
        for (int r = 0; r < N_W + N_F; ++r) {
            int a = s_ord[r];
            if (a < N_W) {
                // dictator is worker w
                int w = a;
                rem_work[w] = 1;                  // dw1 subtraction in Fn (unconditional)
                if (!zero_w[w]) {
                    const short* pw = &s_pw[w * NP1];
                    int j1 = pw[t];                                // ranks 0..63
                    bool a1 = !rem_firm[j1];                       // rem_firm[96]==0 always
                    bool a2 = false;
                    int t2 = t + 64;
                    if (t2 < NP1) { int j2 = pw[t2]; a2 = !rem_firm[j2]; }
                    unsigned long long m1 = __ballot(a1);
                    unsigned long long m2 = __ballot(a2);
                    int k = m1 ? (__ffsll(m1) - 1) : (64 + __ffsll(m2) - 1);
                    int js = pw[k];                                // chosen firm (or 96=unmatch)
                    s_m[w * NP1 + js] = 1;
                    if (js < N_F) { rem_firm[js] = 1; zero_f[js] = 1; }
                }
            } else {
                // dictator is firm f
                int f = a - N_W;
                rem_firm[f] = 1;                  // df1 subtraction in Wn (unconditional)
                if (!zero_f[f]) {
                    const short* pf = &s_pf[f * NP1];
                    int i1 = pf[t];
                    bool a1 = !rem_work[i1];
                    bool a2 = false;
                    int t2 = t + 64;
                    if (t2 < NP1) { int i2 = pf[t2]; a2 = !rem_work[i2]; }
                    unsigned long long m1 = __ballot(a1);
                    unsigned long long m2 = __ballot(a2);
                    int k = m1 ? (__ffsll(m1) - 1) : (64 + __ffsll(m2) - 1);
                    int is = pf[k];                                // chosen worker (or 96=unmatch)
                    s_m[is * NP1 + f] = 1;
                    if (is < N_W) { rem_work[is] = 1; zero_w[is] = 1; }
                }
            }
        }
    }
    __syncthreads();
    for (int i = t; i < NP1 * NP1; i += 256) out[i] = (float)s_m[i];
}

extern "C" void kernel_launch(void* const* d_in, const int* in_sizes, int n_in,
                              void* d_out, int out_size, void* d_ws, size_t ws_size,
                              hipStream_t stream) {
    const float* W = (const float*)d_in[0];
    const float* F = (const float*)d_in[1];
    const float* R = (const float*)d_in[2];
    float* out = (float*)d_out;

    short* pw = (short*)d_ws;                       // 96*97 shorts
    short* pf = pw + N_W * NP1;                     // 96*97 shorts
    short* ord = pf + N_F * NP1;                    // 192 shorts

    int blocks = (TOTAL_DECODE + 255) / 256;
    decode_kernel<<<blocks, 256, 0, stream>>>(W, F, R, pw, pf, ord);
    sd_kernel<<<1, 256, 0, stream>>>(pw, pf, ord, out);
}